// Round 16
// baseline (145.109 us; speedup 1.0000x reference)
//
#include <hip/hip_runtime.h>
#include <math.h>

#define HEADS 4
#define DH 16
#define D 64
#define MAXDEG 64
#define NBKT 8
#define BKT_CAP_LDS 512
#define SENTINEL 0xFFFFFFFFu

typedef unsigned short ushort_t;
typedef unsigned int uint_t;

__device__ __forceinline__ float bf2f(ushort_t u) {
    return __uint_as_float(((uint_t)u) << 16);
}
__device__ __forceinline__ ushort_t f2bf(float f) {
    uint_t u = __float_as_uint(f);
    u = (u + 0x7FFFu + ((u >> 16) & 1u)) >> 16;  // RNE
    return (ushort_t)u;
}
__device__ __forceinline__ float bflo(uint_t u) { return __uint_as_float(u << 16); }
__device__ __forceinline__ float bfhi(uint_t u) { return __uint_as_float(u & 0xFFFF0000u); }

// ---- kernel 1: bucket edges by dst-octant (single read pass) -------------
// Packs (dst<<16)|src (both < 65536). LDS-staged, 16-entry-aligned flushes
// (sentinel-padded) -> all global bucket writes are full 64B lines.
__global__ __launch_bounds__(256) void bucket_kernel(const int* __restrict__ src,
                                                     const int* __restrict__ dst,
                                                     int* __restrict__ gcur,
                                                     uint_t* __restrict__ gbkt,
                                                     int E, int cap, float rb) {
    __shared__ uint_t bbuf[NBKT][BKT_CAP_LDS];  // 16 KB
    __shared__ int bcnt[NBKT];
    __shared__ int bbase[NBKT];

    int tid = threadIdx.x;
    if (tid < NBKT) bcnt[tid] = 0;
    __syncthreads();

    int e0 = (int)((long long)E * blockIdx.x / gridDim.x);
    int e1 = (int)((long long)E * (blockIdx.x + 1) / gridDim.x);
    for (int e = e0 + tid; e < e1; e += 256) {
        int d = dst[e];
        int s = src[e];
        int b = (int)((float)d * rb); if (b > NBKT - 1) b = NBKT - 1;
        uint_t w = ((uint_t)d << 16) | (uint_t)s;
        int p = atomicAdd(&bcnt[b], 1);
        if (p < BKT_CAP_LDS) {
            bbuf[b][p] = w;
        } else {  // overflow fallback (statistically never at 781 edges/block)
            int gp = atomicAdd(&gcur[b], 1);
            gbkt[(size_t)b * cap + gp] = w;
        }
    }
    __syncthreads();

    if (tid < NBKT) {
        int cnt = bcnt[tid]; if (cnt > BKT_CAP_LDS) cnt = BKT_CAP_LDS;
        int pad = (cnt + 15) & ~15;
        for (int i = cnt; i < pad; ++i) bbuf[tid][i] = SENTINEL;
        bbase[tid] = atomicAdd(&gcur[tid], pad);
        bcnt[tid] = pad;
    }
    __syncthreads();

    for (int b = 0; b < NBKT; ++b) {
        int cnt = bcnt[b];
        int base = bbase[b];
        for (int i = tid; i < cnt; i += 256)
            gbkt[(size_t)b * cap + base + i] = bbuf[b][i];
    }
}

// ---- kernel 2: fused q,k,v projection (pure, R13 structure) --------------
__global__ __launch_bounds__(256) void qkv_kernel(const float* __restrict__ x,
                                                  const float* __restrict__ Wq,
                                                  const float* __restrict__ Wk,
                                                  const float* __restrict__ Wv,
                                                  ushort_t* __restrict__ qbf,
                                                  ushort_t* __restrict__ kbf,
                                                  ushort_t* __restrict__ vbf,
                                                  int N) {
    __shared__ ushort_t wq[D][D];   // 8 KB (bf16)
    __shared__ ushort_t wk[D][D];   // 8 KB
    __shared__ ushort_t wv[D][D];   // 8 KB
    __shared__ float xs[16][D];     // 4 KB

    int tid = threadIdx.x;
    for (int i = tid; i < D * D; i += 256) {
        wq[i >> 6][i & 63] = f2bf(Wq[i]);
        wk[i >> 6][i & 63] = f2bf(Wk[i]);
        wv[i >> 6][i & 63] = f2bf(Wv[i]);
    }

    int c = tid & 63;
    int g = tid >> 6;
    int row = tid >> 4;
    int col4 = tid & 15;

    int ntiles = (N + 15) >> 4;
    for (int tile = blockIdx.x; tile < ntiles; tile += gridDim.x) {
        int n0t = tile * 16;
        __syncthreads();
        float4 xv = make_float4(0.f, 0.f, 0.f, 0.f);
        if (n0t + row < N) xv = *(const float4*)(x + (size_t)(n0t + row) * D + col4 * 4);
        *(float4*)&xs[row][col4 * 4] = xv;
        __syncthreads();

        float aq0=0,aq1=0,aq2=0,aq3=0, ak0=0,ak1=0,ak2=0,ak3=0, av0=0,av1=0,av2=0,av3=0;
#pragma unroll 8
        for (int d = 0; d < D; ++d) {
            float wqv = bf2f(wq[d][c]), wkv = bf2f(wk[d][c]), wvv = bf2f(wv[d][c]);
            float x0 = xs[g*4+0][d], x1 = xs[g*4+1][d], x2 = xs[g*4+2][d], x3 = xs[g*4+3][d];
            aq0 += x0*wqv; ak0 += x0*wkv; av0 += x0*wvv;
            aq1 += x1*wqv; ak1 += x1*wkv; av1 += x1*wvv;
            aq2 += x2*wqv; ak2 += x2*wkv; av2 += x2*wvv;
            aq3 += x3*wqv; ak3 += x3*wkv; av3 += x3*wvv;
        }
        int nb = n0t + g * 4;
        if (nb+0 < N) { qbf[(size_t)(nb+0)*D+c]=f2bf(aq0); kbf[(size_t)(nb+0)*D+c]=f2bf(ak0); vbf[(size_t)(nb+0)*D+c]=f2bf(av0); }
        if (nb+1 < N) { qbf[(size_t)(nb+1)*D+c]=f2bf(aq1); kbf[(size_t)(nb+1)*D+c]=f2bf(ak1); vbf[(size_t)(nb+1)*D+c]=f2bf(av1); }
        if (nb+2 < N) { qbf[(size_t)(nb+2)*D+c]=f2bf(aq2); kbf[(size_t)(nb+2)*D+c]=f2bf(ak2); vbf[(size_t)(nb+2)*D+c]=f2bf(av2); }
        if (nb+3 < N) { qbf[(size_t)(nb+3)*D+c]=f2bf(aq3); kbf[(size_t)(nb+3)*D+c]=f2bf(ak3); vbf[(size_t)(nb+3)*D+c]=f2bf(av3); }
    }
}

// ---- kernel 3: XCD-local scatter from buckets into padded CSR ------------
// bid&7 = bucket = XCD (round-robin dispatch heuristic). Each XCD's csr
// footprint is N/8 nodes * 128B ~= 0.8MB + 25KB cursor: L2-resident, so
// each csr line is written back once instead of ~16 times.
__global__ __launch_bounds__(256) void scatter2_kernel(const uint_t* __restrict__ gbkt,
                                                       const int* __restrict__ gcur,
                                                       int* __restrict__ cursor,
                                                       ushort_t* __restrict__ csr,
                                                       int cap) {
    int g     = blockIdx.x & (NBKT - 1);
    int chunk = blockIdx.x >> 3;
    int nch   = gridDim.x >> 3;
    int cnt = gcur[g];
    int i0 = (int)((long long)cnt * chunk / nch);
    int i1 = (int)((long long)cnt * (chunk + 1) / nch);
    const uint_t* bkt = gbkt + (size_t)g * cap;

    for (int i = i0 + threadIdx.x; i < i1; i += 256) {
        uint_t w = bkt[i];
        if (w == SENTINEL) continue;
        int d = (int)(w >> 16);
        int s = (int)(w & 0xFFFFu);
        int pos = atomicAdd(&cursor[d], 1);
        if (pos < MAXDEG) csr[(size_t)d * MAXDEG + pos] = (ushort_t)s;
    }
}

// ---- kernel 4: per-node attention + fused Wo projection (R15, proven) ----
__global__ __launch_bounds__(512) void attn_kernel(const ushort_t* __restrict__ qbf,
                                                   const ushort_t* __restrict__ kbf,
                                                   const ushort_t* __restrict__ vbf,
                                                   const ushort_t* __restrict__ csr,
                                                   const int* __restrict__ cursor,
                                                   const float* __restrict__ Wo,
                                                   float* __restrict__ out,
                                                   int N) {
    __shared__ float wo[D][D];     // 16 KB
    __shared__ float aggsh[8][D];  // 2 KB (per-wave)

    int tid = threadIdx.x;
    for (int i = tid; i < D * D; i += 512) wo[i >> 6][i & 63] = Wo[i];
    __syncthreads();

    int lane = tid & 63;
    int wave = tid >> 6;
    int node = blockIdx.x * 8 + wave;
    if (node >= N) return;

    int hp  = lane & 3;          // phase-1: head
    int el  = lane >> 2;         // phase-1: edge slot 0..15
    int hd  = (lane & 31) >> 3;  // phase-3: head of this lane's dim pair
    int par = lane >> 5;         // phase-3: edge parity
    int dp2 = 2 * (lane & 31);   // phase-3: first dim

    int cnt = cursor[node]; if (cnt > MAXDEG) cnt = MAXDEG;
    const ushort_t* row = csr + (size_t)node * MAXDEG;

    float qr[16];
    {
        const uint4* qp = (const uint4*)(qbf + (size_t)node * D + hp * DH);
        uint4 qa = qp[0], qb = qp[1];
        qr[0]=bflo(qa.x);  qr[1]=bfhi(qa.x);  qr[2]=bflo(qa.y);  qr[3]=bfhi(qa.y);
        qr[4]=bflo(qa.z);  qr[5]=bfhi(qa.z);  qr[6]=bflo(qa.w);  qr[7]=bfhi(qa.w);
        qr[8]=bflo(qb.x);  qr[9]=bfhi(qb.x);  qr[10]=bflo(qb.y); qr[11]=bfhi(qb.y);
        qr[12]=bflo(qb.z); qr[13]=bfhi(qb.z); qr[14]=bflo(qb.w); qr[15]=bfhi(qb.w);
    }

    int s0=0, s1=0, s2=0, s3=0;
    float sc0=-1e30f, sc1=-1e30f, sc2=-1e30f, sc3=-1e30f;

#define PH1SB(sb, sv, scv)                                                      \
    if ((sb) * 16 < cnt) {                                                      \
        int eidx = (sb) * 16 + el;                                              \
        if (eidx < cnt) sv = row[eidx];                                         \
        const uint4* kp = (const uint4*)(kbf + (size_t)sv * D + hp * DH);       \
        uint4 ka = kp[0], kb = kp[1];                                           \
        float dot =                                                             \
          bflo(ka.x)*qr[0]  + bfhi(ka.x)*qr[1]                                  \
        + bflo(ka.y)*qr[2]  + bfhi(ka.y)*qr[3]                                  \
        + bflo(ka.z)*qr[4]  + bfhi(ka.z)*qr[5]                                  \
        + bflo(ka.w)*qr[6]  + bfhi(ka.w)*qr[7]                                  \
        + bflo(kb.x)*qr[8]  + bfhi(kb.x)*qr[9]                                  \
        + bflo(kb.y)*qr[10] + bfhi(kb.y)*qr[11]                                 \
        + bflo(kb.z)*qr[12] + bfhi(kb.z)*qr[13]                                 \
        + bflo(kb.w)*qr[14] + bfhi(kb.w)*qr[15];                                \
        scv = (eidx < cnt) ? dot * 0.25f : -1e30f;                              \
    }
    PH1SB(0, s0, sc0)
    PH1SB(1, s1, sc1)
    PH1SB(2, s2, sc2)
    PH1SB(3, s3, sc3)
#undef PH1SB

    float mloc = fmaxf(fmaxf(sc0, sc1), fmaxf(sc2, sc3));
    mloc = fmaxf(mloc, __shfl_xor(mloc, 4, 64));
    mloc = fmaxf(mloc, __shfl_xor(mloc, 8, 64));
    mloc = fmaxf(mloc, __shfl_xor(mloc, 16, 64));
    mloc = fmaxf(mloc, __shfl_xor(mloc, 32, 64));
    mloc = fmaxf(mloc, -1e9f);

    float pv0 = __expf(sc0 - mloc);
    float pv1 = __expf(sc1 - mloc);
    float pv2 = __expf(sc2 - mloc);
    float pv3 = __expf(sc3 - mloc);
    float ls = (pv0 + pv1) + (pv2 + pv3);
    ls += __shfl_xor(ls, 4, 64);
    ls += __shfl_xor(ls, 8, 64);
    ls += __shfl_xor(ls, 16, 64);
    ls += __shfl_xor(ls, 32, 64);

    float inv = 1.f / (__shfl(ls, hd, 64) + 1e-9f);

    float2 a0 = {0.f, 0.f}, a1 = {0.f, 0.f};
#define PH3SB(sb, sv, pvv)                                                      \
    if ((sb) * 16 < cnt) {                                                      \
        int lim = cnt - (sb) * 16; if (lim > 16) lim = 16;                      \
        for (int e2 = 0; e2 < lim; e2 += 4) {                                   \
            int L0 = 4 * (e2 + par);                                            \
            int ss0 = __shfl(sv, L0, 64);                                       \
            float p0 = __shfl(pvv, L0 + hd, 64);                                \
            uint_t w0 = *(const uint_t*)(vbf + (size_t)ss0 * D + dp2);          \
            a0.x += p0 * bflo(w0);                                              \
            a0.y += p0 * bfhi(w0);                                              \
            int L1 = 4 * (e2 + 2 + par);                                        \
            int ss1 = __shfl(sv, L1, 64);                                       \
            float p1 = __shfl(pvv, L1 + hd, 64);                                \
            uint_t w1 = *(const uint_t*)(vbf + (size_t)ss1 * D + dp2);          \
            a1.x += p1 * bflo(w1);                                              \
            a1.y += p1 * bfhi(w1);                                              \
        }                                                                       \
    }
    PH3SB(0, s0, pv0)
    PH3SB(1, s1, pv1)
    PH3SB(2, s2, pv2)
    PH3SB(3, s3, pv3)
#undef PH3SB

    float ax = a0.x + a1.x, ay = a0.y + a1.y;
    ax += __shfl_xor(ax, 32, 64);
    ay += __shfl_xor(ay, 32, 64);
    if (lane < 32) {
        aggsh[wave][dp2]     = ax * inv;
        aggsh[wave][dp2 + 1] = ay * inv;
    }
    // same-wave LDS RAW: ordered by hardware waitcnt, no barrier needed

    float o = 0.f;
#pragma unroll 8
    for (int d = 0; d < D; ++d) {
        o += aggsh[wave][d] * wo[d][lane];
    }
    out[(size_t)node * D + lane] = o;
}

extern "C" void kernel_launch(void* const* d_in, const int* in_sizes, int n_in,
                              void* d_out, int out_size, void* d_ws, size_t ws_size,
                              hipStream_t stream) {
    const float* x  = (const float*)d_in[0];
    const float* Wq = (const float*)d_in[1];
    const float* Wk = (const float*)d_in[2];
    const float* Wv = (const float*)d_in[3];
    const float* Wo = (const float*)d_in[4];
    const int* src  = (const int*)d_in[5];
    const int* dst  = (const int*)d_in[6];
    float* out = (float*)d_out;

    int N = in_sizes[0] / D;
    int E = in_sizes[5];
    int cap = E / 4;  // per-bucket capacity (expected E/8 + padding slack)

    // workspace layout (cursor, gcur adjacent -> single memset)
    char* ws = (char*)d_ws;
    ushort_t* qbf   = (ushort_t*)ws;  ws += (size_t)N * D * 2;
    ushort_t* kbf   = (ushort_t*)ws;  ws += (size_t)N * D * 2;
    ushort_t* vbf   = (ushort_t*)ws;  ws += (size_t)N * D * 2;
    int* cursor     = (int*)ws;       ws += (size_t)N * 4;
    int* gcur       = (int*)ws;       ws += 64;  // 8 ints, padded
    ushort_t* csr   = (ushort_t*)ws;  ws += (size_t)N * MAXDEG * 2;
    uint_t* gbkt    = (uint_t*)ws;    ws += (size_t)NBKT * cap * 4;

    int nTiles16 = (N + 15) / 16;
    int gemmGrid = nTiles16 < 2048 ? nTiles16 : 2048;
    int attnGrid = (N + 7) / 8;
    float rb = (float)NBKT / (float)N;

    hipMemsetAsync(cursor, 0, (size_t)N * 4 + 64, stream);
    bucket_kernel<<<1024, 256, 0, stream>>>(src, dst, gcur, gbkt, E, cap, rb);
    qkv_kernel<<<gemmGrid, 256, 0, stream>>>(x, Wq, Wk, Wv, qbf, kbf, vbf, N);
    scatter2_kernel<<<2048, 256, 0, stream>>>(gbkt, gcur, cursor, csr, cap);
    attn_kernel<<<attnGrid, 512, 0, stream>>>(qbf, kbf, vbf, csr, cursor, Wo, out, N);
}

// Round 17
// 121.899 us; speedup vs baseline: 1.1904x; 1.1904x over previous
//
#include <hip/hip_runtime.h>
#include <math.h>

#define HEADS 4
#define DH 16
#define D 64
#define MAXDEG 64

typedef unsigned short ushort_t;
typedef unsigned int uint_t;

__device__ __forceinline__ float bf2f(ushort_t u) {
    return __uint_as_float(((uint_t)u) << 16);
}
__device__ __forceinline__ ushort_t f2bf(float f) {
    uint_t u = __float_as_uint(f);
    u = (u + 0x7FFFu + ((u >> 16) & 1u)) >> 16;  // RNE
    return (ushort_t)u;
}
__device__ __forceinline__ float bflo(uint_t u) { return __uint_as_float(u << 16); }
__device__ __forceinline__ float bfhi(uint_t u) { return __uint_as_float(u & 0xFFFF0000u); }

// ---- kernel 1: scatter-FIRST + q,k,v projection second -------------------
// Scatter's cost is atomic/fabric queue DRAIN, not CU occupancy (VALUBusy
// 0.3% standalone). Issuing the ~1.5 edges/thread atomics at kernel start
// lets waves stall-release progressively into the qkv phase, overlapping
// the drain with qkv's VALU/LDS work. (R13 order — qkv first — left the
// drain exposed at the end: fused time = qkv + scatter serially.)
__global__ __launch_bounds__(256) void scatter_qkv_kernel(
        const float* __restrict__ x,
        const float* __restrict__ Wq,
        const float* __restrict__ Wk,
        const float* __restrict__ Wv,
        ushort_t* __restrict__ qbf,
        ushort_t* __restrict__ kbf,
        ushort_t* __restrict__ vbf,
        const int* __restrict__ src,
        const int* __restrict__ dst,
        int* __restrict__ cursor,
        ushort_t* __restrict__ csr,
        int N, int E) {
    __shared__ ushort_t wq[D][D];   // 8 KB (bf16)
    __shared__ ushort_t wk[D][D];   // 8 KB
    __shared__ ushort_t wv[D][D];   // 8 KB
    __shared__ float xs[16][D];     // 4 KB

    int tid = threadIdx.x;

    // ---- phase A: scatter (issue atomics immediately) ----
    {
        int e0 = (int)((long long)E * blockIdx.x / gridDim.x);
        int e1 = (int)((long long)E * (blockIdx.x + 1) / gridDim.x);
        for (int e = e0 + tid; e < e1; e += 256) {
            int d = dst[e];
            int s = src[e];
            int pos = atomicAdd(&cursor[d], 1);
            if (pos < MAXDEG) csr[(size_t)d * MAXDEG + pos] = (ushort_t)s;
        }
    }

    // ---- phase B: qkv projection (overlaps the scatter drain) ----
    for (int i = tid; i < D * D; i += 256) {
        wq[i >> 6][i & 63] = f2bf(Wq[i]);
        wk[i >> 6][i & 63] = f2bf(Wk[i]);
        wv[i >> 6][i & 63] = f2bf(Wv[i]);
    }

    int c = tid & 63;
    int g = tid >> 6;
    int row = tid >> 4;
    int col4 = tid & 15;

    int ntiles = (N + 15) >> 4;
    for (int tile = blockIdx.x; tile < ntiles; tile += gridDim.x) {
        int n0t = tile * 16;
        __syncthreads();
        float4 xv = make_float4(0.f, 0.f, 0.f, 0.f);
        if (n0t + row < N) xv = *(const float4*)(x + (size_t)(n0t + row) * D + col4 * 4);
        *(float4*)&xs[row][col4 * 4] = xv;
        __syncthreads();

        float aq0=0,aq1=0,aq2=0,aq3=0, ak0=0,ak1=0,ak2=0,ak3=0, av0=0,av1=0,av2=0,av3=0;
#pragma unroll 8
        for (int d = 0; d < D; ++d) {
            float wqv = bf2f(wq[d][c]), wkv = bf2f(wk[d][c]), wvv = bf2f(wv[d][c]);
            float x0 = xs[g*4+0][d], x1 = xs[g*4+1][d], x2 = xs[g*4+2][d], x3 = xs[g*4+3][d];
            aq0 += x0*wqv; ak0 += x0*wkv; av0 += x0*wvv;
            aq1 += x1*wqv; ak1 += x1*wkv; av1 += x1*wvv;
            aq2 += x2*wqv; ak2 += x2*wkv; av2 += x2*wvv;
            aq3 += x3*wqv; ak3 += x3*wkv; av3 += x3*wvv;
        }
        int nb = n0t + g * 4;
        if (nb+0 < N) { qbf[(size_t)(nb+0)*D+c]=f2bf(aq0); kbf[(size_t)(nb+0)*D+c]=f2bf(ak0); vbf[(size_t)(nb+0)*D+c]=f2bf(av0); }
        if (nb+1 < N) { qbf[(size_t)(nb+1)*D+c]=f2bf(aq1); kbf[(size_t)(nb+1)*D+c]=f2bf(ak1); vbf[(size_t)(nb+1)*D+c]=f2bf(av1); }
        if (nb+2 < N) { qbf[(size_t)(nb+2)*D+c]=f2bf(aq2); kbf[(size_t)(nb+2)*D+c]=f2bf(ak2); vbf[(size_t)(nb+2)*D+c]=f2bf(av2); }
        if (nb+3 < N) { qbf[(size_t)(nb+3)*D+c]=f2bf(aq3); kbf[(size_t)(nb+3)*D+c]=f2bf(ak3); vbf[(size_t)(nb+3)*D+c]=f2bf(av3); }
    }
}

// ---- kernel 2: per-node attention + fused Wo projection (R15, proven) ----
// 512 threads = 8 waves = 8 nodes/block; softmax/agg in registers;
// Wo staged once per block; epilogue hides in the idle LDS pipe.
__global__ __launch_bounds__(512) void attn_kernel(const ushort_t* __restrict__ qbf,
                                                   const ushort_t* __restrict__ kbf,
                                                   const ushort_t* __restrict__ vbf,
                                                   const ushort_t* __restrict__ csr,
                                                   const int* __restrict__ cursor,
                                                   const float* __restrict__ Wo,
                                                   float* __restrict__ out,
                                                   int N) {
    __shared__ float wo[D][D];     // 16 KB
    __shared__ float aggsh[8][D];  // 2 KB (per-wave)

    int tid = threadIdx.x;
    for (int i = tid; i < D * D; i += 512) wo[i >> 6][i & 63] = Wo[i];
    __syncthreads();

    int lane = tid & 63;
    int wave = tid >> 6;
    int node = blockIdx.x * 8 + wave;
    if (node >= N) return;

    int hp  = lane & 3;          // phase-1: head
    int el  = lane >> 2;         // phase-1: edge slot 0..15
    int hd  = (lane & 31) >> 3;  // phase-3: head of this lane's dim pair
    int par = lane >> 5;         // phase-3: edge parity
    int dp2 = 2 * (lane & 31);   // phase-3: first dim

    int cnt = cursor[node]; if (cnt > MAXDEG) cnt = MAXDEG;
    const ushort_t* row = csr + (size_t)node * MAXDEG;

    float qr[16];
    {
        const uint4* qp = (const uint4*)(qbf + (size_t)node * D + hp * DH);
        uint4 qa = qp[0], qb = qp[1];
        qr[0]=bflo(qa.x);  qr[1]=bfhi(qa.x);  qr[2]=bflo(qa.y);  qr[3]=bfhi(qa.y);
        qr[4]=bflo(qa.z);  qr[5]=bfhi(qa.z);  qr[6]=bflo(qa.w);  qr[7]=bfhi(qa.w);
        qr[8]=bflo(qb.x);  qr[9]=bfhi(qb.x);  qr[10]=bflo(qb.y); qr[11]=bfhi(qb.y);
        qr[12]=bflo(qb.z); qr[13]=bfhi(qb.z); qr[14]=bflo(qb.w); qr[15]=bfhi(qb.w);
    }

    int s0=0, s1=0, s2=0, s3=0;
    float sc0=-1e30f, sc1=-1e30f, sc2=-1e30f, sc3=-1e30f;

#define PH1SB(sb, sv, scv)                                                      \
    if ((sb) * 16 < cnt) {                                                      \
        int eidx = (sb) * 16 + el;                                              \
        if (eidx < cnt) sv = row[eidx];                                         \
        const uint4* kp = (const uint4*)(kbf + (size_t)sv * D + hp * DH);       \
        uint4 ka = kp[0], kb = kp[1];                                           \
        float dot =                                                             \
          bflo(ka.x)*qr[0]  + bfhi(ka.x)*qr[1]                                  \
        + bflo(ka.y)*qr[2]  + bfhi(ka.y)*qr[3]                                  \
        + bflo(ka.z)*qr[4]  + bfhi(ka.z)*qr[5]                                  \
        + bflo(ka.w)*qr[6]  + bfhi(ka.w)*qr[7]                                  \
        + bflo(kb.x)*qr[8]  + bfhi(kb.x)*qr[9]                                  \
        + bflo(kb.y)*qr[10] + bfhi(kb.y)*qr[11]                                 \
        + bflo(kb.z)*qr[12] + bfhi(kb.z)*qr[13]                                 \
        + bflo(kb.w)*qr[14] + bfhi(kb.w)*qr[15];                                \
        scv = (eidx < cnt) ? dot * 0.25f : -1e30f;                              \
    }
    PH1SB(0, s0, sc0)
    PH1SB(1, s1, sc1)
    PH1SB(2, s2, sc2)
    PH1SB(3, s3, sc3)
#undef PH1SB

    float mloc = fmaxf(fmaxf(sc0, sc1), fmaxf(sc2, sc3));
    mloc = fmaxf(mloc, __shfl_xor(mloc, 4, 64));
    mloc = fmaxf(mloc, __shfl_xor(mloc, 8, 64));
    mloc = fmaxf(mloc, __shfl_xor(mloc, 16, 64));
    mloc = fmaxf(mloc, __shfl_xor(mloc, 32, 64));
    mloc = fmaxf(mloc, -1e9f);

    float pv0 = __expf(sc0 - mloc);
    float pv1 = __expf(sc1 - mloc);
    float pv2 = __expf(sc2 - mloc);
    float pv3 = __expf(sc3 - mloc);
    float ls = (pv0 + pv1) + (pv2 + pv3);
    ls += __shfl_xor(ls, 4, 64);
    ls += __shfl_xor(ls, 8, 64);
    ls += __shfl_xor(ls, 16, 64);
    ls += __shfl_xor(ls, 32, 64);

    float inv = 1.f / (__shfl(ls, hd, 64) + 1e-9f);

    float2 a0 = {0.f, 0.f}, a1 = {0.f, 0.f};
#define PH3SB(sb, sv, pvv)                                                      \
    if ((sb) * 16 < cnt) {                                                      \
        int lim = cnt - (sb) * 16; if (lim > 16) lim = 16;                      \
        for (int e2 = 0; e2 < lim; e2 += 4) {                                   \
            int L0 = 4 * (e2 + par);                                            \
            int ss0 = __shfl(sv, L0, 64);                                       \
            float p0 = __shfl(pvv, L0 + hd, 64);                                \
            uint_t w0 = *(const uint_t*)(vbf + (size_t)ss0 * D + dp2);          \
            a0.x += p0 * bflo(w0);                                              \
            a0.y += p0 * bfhi(w0);                                              \
            int L1 = 4 * (e2 + 2 + par);                                        \
            int ss1 = __shfl(sv, L1, 64);                                       \
            float p1 = __shfl(pvv, L1 + hd, 64);                                \
            uint_t w1 = *(const uint_t*)(vbf + (size_t)ss1 * D + dp2);          \
            a1.x += p1 * bflo(w1);                                              \
            a1.y += p1 * bfhi(w1);                                              \
        }                                                                       \
    }
    PH3SB(0, s0, pv0)
    PH3SB(1, s1, pv1)
    PH3SB(2, s2, pv2)
    PH3SB(3, s3, pv3)
#undef PH3SB

    float ax = a0.x + a1.x, ay = a0.y + a1.y;
    ax += __shfl_xor(ax, 32, 64);
    ay += __shfl_xor(ay, 32, 64);
    if (lane < 32) {
        aggsh[wave][dp2]     = ax * inv;
        aggsh[wave][dp2 + 1] = ay * inv;
    }
    // same-wave LDS RAW: ordered by hardware waitcnt, no barrier needed

    float o = 0.f;
#pragma unroll 8
    for (int d = 0; d < D; ++d) {
        o += aggsh[wave][d] * wo[d][lane];
    }
    out[(size_t)node * D + lane] = o;
}

extern "C" void kernel_launch(void* const* d_in, const int* in_sizes, int n_in,
                              void* d_out, int out_size, void* d_ws, size_t ws_size,
                              hipStream_t stream) {
    const float* x  = (const float*)d_in[0];
    const float* Wq = (const float*)d_in[1];
    const float* Wk = (const float*)d_in[2];
    const float* Wv = (const float*)d_in[3];
    const float* Wo = (const float*)d_in[4];
    const int* src  = (const int*)d_in[5];
    const int* dst  = (const int*)d_in[6];
    float* out = (float*)d_out;

    int N = in_sizes[0] / D;
    int E = in_sizes[5];

    // workspace layout
    char* ws = (char*)d_ws;
    ushort_t* qbf   = (ushort_t*)ws;  ws += (size_t)N * D * 2;
    ushort_t* kbf   = (ushort_t*)ws;  ws += (size_t)N * D * 2;
    ushort_t* vbf   = (ushort_t*)ws;  ws += (size_t)N * D * 2;
    int* cursor     = (int*)ws;       ws += (size_t)N * 4;
    ushort_t* csr   = (ushort_t*)ws;  ws += (size_t)N * MAXDEG * 2;

    int attnGrid = (N + 7) / 8;

    hipMemsetAsync(cursor, 0, (size_t)N * 4, stream);
    scatter_qkv_kernel<<<2048, 256, 0, stream>>>(x, Wq, Wk, Wv, qbf, kbf, vbf,
                                                 src, dst, cursor, csr, N, E);
    attn_kernel<<<attnGrid, 512, 0, stream>>>(qbf, kbf, vbf, csr, cursor, Wo, out, N);
}